// Round 10
// baseline (208.878 us; speedup 1.0000x reference)
//
#include <hip/hip_runtime.h>

typedef __attribute__((ext_vector_type(8))) short short8;
typedef __attribute__((ext_vector_type(4))) float f32x4;

#define N_ATOMS 4096
#define N_NEIGH 32
#define IN_F 128
#define HID 256
#define OUT_F 128
#define N_SPECIES 64

// RNE round to bf16 (weights; 2-term split keeps only wh).
__device__ __forceinline__ unsigned short f2bf(float f) {
  unsigned u = __float_as_uint(f);
  u += 0x7FFF + ((u >> 16) & 1);
  return (unsigned short)(u >> 16);
}
// Truncation hi/lo split for activations (hi exact chop, lo exact residual).
struct HL { short h, l; };
__device__ __forceinline__ HL split2(float v) {
  unsigned u = __float_as_uint(v);
  float lo = v - __uint_as_float(u & 0xFFFF0000u);
  HL o;
  o.h = (short)(u >> 16);
  o.l = (short)(__float_as_uint(lo) >> 16);
  return o;
}

// ---------- kernel 1: (block 0) counting sort | (blocks 1..) W -> bf16 RNE ----------
// W1 is written ROW-PERMUTED within each 32-row chunk: dest position pl holds
// physical row 8*((pl>>2)&3) + 4*((pl>>4)&1) + (pl&3), so the mlp kernel's
// swapped-operand layer-1 output lands with lane h = 8q+j (verified in r8).
__global__ __launch_bounds__(256) void prep_kernel(
    const float* __restrict__ W1, const float* __restrict__ W2,
    const int* __restrict__ sp_idx,
    unsigned short* __restrict__ w1p, unsigned short* __restrict__ w2h,
    int* __restrict__ atom_order) {
  const int t = threadIdx.x;
  if (blockIdx.x == 0) {
    __shared__ int cnt[N_SPECIES], cur[N_SPECIES];
    if (t < N_SPECIES) cnt[t] = 0;
    __syncthreads();
    for (int a = t; a < N_ATOMS; a += 256) atomicAdd(&cnt[sp_idx[a]], 1);
    __syncthreads();
    if (t == 0) {
      int o = 0;
      for (int s = 0; s < N_SPECIES; ++s) { cur[s] = o; o += cnt[s]; }
    }
    __syncthreads();
    for (int a = t; a < N_ATOMS; a += 256) {
      int s = sp_idx[a];
      atom_order[atomicAdd(&cur[s], 1)] = a;
    }
    return;
  }
  const int NV = (N_SPECIES * HID * IN_F) / 4;  // ushort4/float4 groups per matrix
  const int nsplit = (gridDim.x - 1) * 256;
  for (int v = (blockIdx.x - 1) * 256 + t; v < 2 * NV; v += nsplit) {
    float4 f;
    unsigned short* dst;
    int j;
    if (v < NV) {
      j = v;                                   // dest index in w1p
      const int s0 = j >> 13;                  // HID*IN_F/4 = 8192 groups/species
      const int rem = j & 8191;
      const int drow = rem >> 5;               // IN_F/4 = 32 groups/row
      const int c4 = rem & 31;
      const int pl = drow & 31;
      const int srow = (drow & ~31) + ((pl >> 2) & 3) * 8 + ((pl >> 4) & 1) * 4 + (pl & 3);
      f = ((const float4*)W1)[(s0 * HID + srow) * (IN_F / 4) + c4];
      dst = w1p;
    } else {
      j = v - NV;
      f = ((const float4*)W2)[j];
      dst = w2h;
    }
    ushort4 h;
    h.x = f2bf(f.x); h.y = f2bf(f.y); h.z = f2bf(f.z); h.w = f2bf(f.w);
    ((ushort4*)dst)[j] = h;
  }
}

// ---------- kernel 2: LDS-free-weights MLP, 1 wave = 1 atom, zero barriers ----------
// Grid 512 x 512 threads = 4096 waves = 4096 atoms. Weights read directly
// global(L2)->VGPR per MFMA operand (XCD-chunked sorted atoms keep each XCD's
// species working set ~1 MB, L2-resident). LDS = ONLY the per-wave 4 KB output
// transpose slab (32 KB/block -> 2 blocks/CU, 4 waves/SIMD, 2x round 8).
// Layer 1 swapped: xT = mfma(A=W1p, B=feat); in-register SiLU+split (lane h=8q+j);
// layer 2 swapped: oT += mfma(A=W2, B=xh/xl). Per-atom slab transpose epilogue.
__global__ __launch_bounds__(512, 2) void mlp_kernel(
    const float* __restrict__ feat,
    const float* __restrict__ b1g, const float* __restrict__ b2g,
    const unsigned short* __restrict__ w1p, const unsigned short* __restrict__ w2h,
    const int* __restrict__ atom_order, const int* __restrict__ sp_idx,
    float* __restrict__ out) {
  __shared__ char smem[8][4096];

  const int bid = blockIdx.x;
  const int orig = (bid & 7) * 64 + (bid >> 3);   // XCD-chunked, bijective over 512
  const int wave = threadIdx.x >> 6, lane = threadIdx.x & 63;
  const int q = lane >> 4, r = lane & 15;

  const int atom = atom_order[orig * 8 + wave];
  const int s = sp_idx[atom];
  const char* gw1 = (const char*)w1p + (long)s * (HID * IN_F * 2);
  const char* gw2 = (const char*)w2h + (long)s * (OUT_F * HID * 2);
  const float* b1s = b1g + s * HID;
  const float* b2s = b2g + s * OUT_F;
  char* slab = smem[wave];

  // ---- features -> bf16 hi/lo B-frags: lane holds feat[n=16nt+r][i=32ks+8q+j]
  short8 fh[2][4], fl[2][4];
  {
    const float* fb = feat + (long)atom * (N_NEIGH * IN_F);
#pragma unroll
    for (int nt = 0; nt < 2; ++nt)
#pragma unroll
      for (int ks = 0; ks < 4; ++ks) {
        const float* ptr = fb + (16 * nt + r) * IN_F + 32 * ks + 8 * q;
        float4 v0 = *(const float4*)ptr;
        float4 v1 = *(const float4*)(ptr + 4);
        float vv[8] = {v0.x, v0.y, v0.z, v0.w, v1.x, v1.y, v1.z, v1.w};
        short8 h8, l8;
#pragma unroll
        for (int j = 0; j < 8; ++j) {
          HL hl = split2(vv[j]);
          h8[j] = hl.h;
          l8[j] = hl.l;
        }
        fh[nt][ks] = h8;
        fl[nt][ks] = l8;
      }
  }

  f32x4 oacc[8][2] = {};  // [ot][nt]: lane(q,r) holds out^T[o=16ot+4q+reg][n=16nt+r]

  for (int hc = 0; hc < 8; ++hc) {
    // ---- layer 1 swapped: xT[ht][nt] = sum_ks mfma(A=W1p-row, B=feat)
    f32x4 xacc[2][2] = {};
#pragma unroll
    for (int ks = 0; ks < 4; ++ks) {
      const int ib = (32 * ks + 8 * q) * 2;
#pragma unroll
      for (int ht = 0; ht < 2; ++ht) {
        const int pos = 32 * hc + 16 * ht + r;
        short8 aw = *(const short8*)(gw1 + pos * 256 + ib);
        xacc[ht][0] = __builtin_amdgcn_mfma_f32_16x16x32_bf16(aw, fh[0][ks], xacc[ht][0], 0, 0, 0);
        xacc[ht][1] = __builtin_amdgcn_mfma_f32_16x16x32_bf16(aw, fh[1][ks], xacc[ht][1], 0, 0, 0);
        xacc[ht][0] = __builtin_amdgcn_mfma_f32_16x16x32_bf16(aw, fl[0][ks], xacc[ht][0], 0, 0, 0);
        xacc[ht][1] = __builtin_amdgcn_mfma_f32_16x16x32_bf16(aw, fl[1][ks], xacc[ht][1], 0, 0, 0);
      }
    }
    // ---- bias + SiLU + split + pack IN REGISTERS: lane's h = 8q + (4ht+reg)
    short8 xh[2], xl[2];
#pragma unroll
    for (int ht = 0; ht < 2; ++ht) {
      const float4 b1c = *(const float4*)(b1s + hc * 32 + 8 * q + 4 * ht);
      const float bb[4] = {b1c.x, b1c.y, b1c.z, b1c.w};
#pragma unroll
      for (int nt = 0; nt < 2; ++nt)
#pragma unroll
        for (int reg = 0; reg < 4; ++reg) {
          float v = xacc[ht][nt][reg] + bb[reg];
          v = v * __builtin_amdgcn_rcpf(1.0f + __expf(-v));
          HL hl = split2(v);
          xh[nt][4 * ht + reg] = hl.h;
          xl[nt][4 * ht + reg] = hl.l;
        }
    }
    // ---- layer 2 swapped: oaccT += mfma(A=W2, B=xh) + mfma(A=W2, B=xl)
    const int kb = 64 * hc + 16 * q;
#pragma unroll
    for (int ot = 0; ot < 8; ++ot) {
      short8 aw = *(const short8*)(gw2 + (16 * ot + r) * 512 + kb);
      oacc[ot][0] = __builtin_amdgcn_mfma_f32_16x16x32_bf16(aw, xh[0], oacc[ot][0], 0, 0, 0);
      oacc[ot][1] = __builtin_amdgcn_mfma_f32_16x16x32_bf16(aw, xh[1], oacc[ot][1], 0, 0, 0);
      oacc[ot][0] = __builtin_amdgcn_mfma_f32_16x16x32_bf16(aw, xl[0], oacc[ot][0], 0, 0, 0);
      oacc[ot][1] = __builtin_amdgcn_mfma_f32_16x16x32_bf16(aw, xl[1], oacc[ot][1], 0, 0, 0);
    }
  }

  // ---- epilogue: per-wave slab transpose (o-major -> n-major), once per atom.
  float* ob = out + (long)atom * (N_NEIGH * OUT_F);
#pragma unroll
  for (int g = 0; g < 4; ++g) {       // 32-o slab: ot = 2g, 2g+1
#pragma unroll
    for (int oh = 0; oh < 2; ++oh) {  // write: b128 at [n=16nt+r][o_loc=16*oh+4q]
      const int ot = 2 * g + oh;
      const float4 b2c = *(const float4*)(b2s + 16 * ot + 4 * q);
      const float bb[4] = {b2c.x, b2c.y, b2c.z, b2c.w};
#pragma unroll
      for (int nt = 0; nt < 2; ++nt) {
        f32x4 v;
#pragma unroll
        for (int reg = 0; reg < 4; ++reg) v[reg] = oacc[ot][nt][reg] + bb[reg];
        const int n = 16 * nt + r;
        const int byte = n * 128 + (((16 * oh + 4 * q) * 4) ^ ((n & 7) << 4));
        *(f32x4*)(slab + byte) = v;
      }
    }
    __builtin_amdgcn_s_waitcnt(0);  // slab writes visible to this wave
#pragma unroll
    for (int m = 0; m < 4; ++m) {   // read rows n-major, store 128B-contiguous
      const int n = m * 8 + (lane >> 3);
      const int cb = ((lane & 7) * 16) ^ ((n & 7) << 4);
      float4 v = *(const float4*)(slab + n * 128 + cb);
      *(float4*)(ob + n * OUT_F + 32 * g + (lane & 7) * 4) = v;
    }
    __builtin_amdgcn_s_waitcnt(0);  // drain before overwriting slab next g
  }
}

extern "C" void kernel_launch(void* const* d_in, const int* in_sizes, int n_in,
                              void* d_out, int out_size, void* d_ws, size_t ws_size,
                              hipStream_t stream) {
  const float* feat = (const float*)d_in[0];
  const int* sp     = (const int*)d_in[1];
  const float* W1   = (const float*)d_in[2];
  const float* b1   = (const float*)d_in[3];
  const float* W2   = (const float*)d_in[4];
  const float* b2   = (const float*)d_in[5];
  float* out = (float*)d_out;

  char* ws = (char*)d_ws;
  unsigned short* w1p = (unsigned short*)(ws + 0);
  unsigned short* w2h = (unsigned short*)(ws + 4194304);
  int* atom_order = (int*)(ws + 8388608);

  hipLaunchKernelGGL(prep_kernel, dim3(1025), dim3(256), 0, stream,
                     W1, W2, sp, w1p, w2h, atom_order);
  hipLaunchKernelGGL(mlp_kernel, dim3(512), dim3(512), 0, stream,
                     feat, b1, b2, w1p, w2h, atom_order, sp, out);
}